// Round 5
// baseline (192.207 us; speedup 1.0000x reference)
//
#include <hip/hip_runtime.h>
#include <math.h>

#define B_    8
#define CIN   64
#define COUT  128
#define H_    130
#define NPIX  (H_*H_)            // 16900
#define NPX   (B_*NPIX)          // 135200 flat pixels
#define IMW   132                // padded img width/height (zero ring)
#define ROWE  (8*IMW*8)          // 8448 elems per (b,yy) row slab

typedef __attribute__((ext_vector_type(8))) short short8;   // 8 bf16 (A/B frag)
typedef __attribute__((ext_vector_type(4))) float f32x4;    // MFMA acc

__device__ __forceinline__ ushort f2bf(float f) {
    uint u = __builtin_bit_cast(uint, f);
    uint r = (u + 0x7FFFu + ((u >> 16) & 1u)) >> 16;
    return (ushort)r;
}

// ---------------- BN stage 1: per-(c,b) plane partial sum/sumsq ---------------
__global__ __launch_bounds__(256) void bn_stage1(
    const float* __restrict__ x, float* __restrict__ part)
{
    const int c = blockIdx.x, b = blockIdx.y, tid = threadIdx.x;
    const float4* p = (const float4*)(x + ((size_t)b*CIN + c)*NPIX);
    float s = 0.f, q = 0.f;
    for (int i = tid; i < NPIX/4; i += 256) {   // 16900/4 = 4225 exactly
        float4 v = p[i];
        s += v.x + v.y + v.z + v.w;
        q += v.x*v.x + v.y*v.y + v.z*v.z + v.w*v.w;
    }
    #pragma unroll
    for (int off = 32; off; off >>= 1) { s += __shfl_down(s, off); q += __shfl_down(q, off); }
    __shared__ float ss[4], qq[4];
    if ((tid & 63) == 0) { ss[tid >> 6] = s; qq[tid >> 6] = q; }
    __syncthreads();
    if (tid == 0) {
        s = ss[0] + ss[1] + ss[2] + ss[3];
        q = qq[0] + qq[1] + qq[2] + qq[3];
        part[(c*B_ + b)*2]     = s;
        part[(c*B_ + b)*2 + 1] = q;
    }
}

// ------- fused: weight prep (f32 [co][ci][3][3] -> bf16 [co][dydx][ci]) -------
// ------- + BN stage 2 (combine partials -> affine a,b) on block 0 ------------
__global__ __launch_bounds__(256) void wprep_bn(
    const float* __restrict__ w, const float* __restrict__ part,
    const float* __restrict__ gamma, const float* __restrict__ beta,
    ushort* __restrict__ wT, float* __restrict__ abuf, float* __restrict__ bbuf)
{
    int i = blockIdx.x*256 + threadIdx.x;        // 288*256 = 73728 = 128*576
    int co = i / 576, k = i - co*576;
    int dydx = k >> 6, ci = k & 63;
    wT[i] = f2bf(w[co*576 + ci*9 + dydx]);
    if (blockIdx.x == 0 && threadIdx.x < 64) {
        int c = threadIdx.x;
        float s = 0.f, q = 0.f;
        for (int b = 0; b < B_; ++b) { s += part[(c*B_+b)*2]; q += part[(c*B_+b)*2+1]; }
        float mean = s * (1.0f/135200.f);
        float var  = q * (1.0f/135200.f) - mean*mean;
        float a = gamma[c] / sqrtf(var + 1e-4f);
        abuf[c] = a;
        bbuf[c] = beta[c] - mean * a;
    }
}

// -------- binfold v2: BN-apply + bin_active + col2im, [b][yy][cg][xx][ci8] ----
// grid z = 4 ci-groups of 16; each wave owns 4 ci, loads hoisted for ILP.
__global__ __launch_bounds__(256) void binfold(
    const float* __restrict__ x, const float* __restrict__ abuf,
    const float* __restrict__ bbuf, ushort* __restrict__ img)
{
    __shared__ __align__(16) ushort tile[H_*18];   // [xp][ci16 +2 pad]
    __shared__ float absrow[4][132];
    __shared__ float wsum[4][24];
    const int yy = blockIdx.x, b = blockIdx.y, zg = blockIdx.z;
    const int tid = threadIdx.x, wv = tid >> 6, lane = tid & 63;
    uint* rowU = (uint*)(img + (size_t)(b*IMW + yy)*ROWE);
    const int cgBase = zg*2;

    if (yy == 0 || yy == IMW-1) {                  // border row: zero our slice
        for (int i = tid; i < 2*IMW*4; i += 256)
            rowU[cgBase*IMW*4 + i] = 0u;
        return;
    }
    const int y = yy - 1;
    const float county = (float)min(min(y + 1, 3), H_ - y);

    // hoisted loads: 4 ci rows per wave, all issued up-front
    const int ci0 = zg*16 + wv*4;
    float v0[4], v1[4], v2[4];
    #pragma unroll
    for (int it = 0; it < 4; ++it) {
        const int ci = ci0 + it;
        const float* row = x + (((size_t)b*CIN + ci)*H_ + y)*H_;
        const float a = abuf[ci], bb = bbuf[ci];
        v0[it] = a*row[lane]      + bb;
        v1[it] = a*row[lane + 64] + bb;
        v2[it] = (lane < 2) ? (a*row[lane + 128] + bb) : 0.f;
    }

    #pragma unroll
    for (int it = 0; it < 4; ++it) {
        const int cl = wv*4 + it;                  // ci_l within block, 0..15
        absrow[wv][lane]      = fabsf(v0[it]);
        absrow[wv][lane + 64] = fabsf(v1[it]);
        if (lane < 2) absrow[wv][lane + 128] = fabsf(v2[it]);
        asm volatile("s_waitcnt lgkmcnt(0)" ::: "memory");
        if (lane < 24) {
            int j = lane >> 3, bx = lane & 7;
            int s = j + bx*16;
            float acc = 0.f;
            #pragma unroll
            for (int t = 0; t < 16; ++t) acc += absrow[wv][s + t];
            wsum[wv][j*8 + bx] = acc;
        }
        asm volatile("s_waitcnt lgkmcnt(0)" ::: "memory");
        #pragma unroll
        for (int rep = 0; rep < 3; ++rep) {
            int xp = lane + rep*64;
            if (xp < H_) {
                float v = (rep == 0) ? v0[it] : (rep == 1) ? v1[it] : v2[it];
                float sgn = (v > 0.f) ? 1.f : ((v < 0.f) ? -1.f : 0.f);
                float sum = 0.f;
                #pragma unroll
                for (int j = 0; j < 3; ++j) {
                    int ox = xp - j;
                    if ((unsigned)ox < 128u) sum += wsum[wv][j*8 + (ox >> 4)];
                }
                tile[xp*18 + cl] = f2bf(sgn * county * sum * 0.0625f);
            }
        }
        asm volatile("s_waitcnt lgkmcnt(0)" ::: "memory");   // absrow reuse guard
    }
    __syncthreads();
    // store slice: cg pair, real cols, then zero side columns
    const uint* tU = (const uint*)tile;
    for (int i = tid; i < H_*8; i += 256) {        // 1040 uints
        int xp = i >> 3, p = i & 7;
        rowU[((cgBase + (p >> 2))*IMW + xp + 1)*4 + (p & 3)] = tU[xp*9 + p];
    }
    if (tid < 16) {
        int cg = cgBase + (tid >> 3), side = (tid >> 2) & 1, u = tid & 3;
        rowU[(cg*IMW + (side ? (IMW-1) : 0))*4 + u] = 0u;
    }
}

// ---------------- conv v3: full-row block, 64x80 wave tiles, A prefetch -------
// Block = (y,b). LDS = rows y-1..y+1 contiguous (50.7 KB). 4 waves = (mh,nh):
// wave covers co mh*64+0..63 (4 mt), px nh*80+0..79 (5 nt). K = 18 steps of 32.
__global__ __launch_bounds__(256, 3) void conv_mfma(
    const ushort* __restrict__ img, const ushort* __restrict__ wT,
    const float* __restrict__ bias, float* __restrict__ out)
{
    __shared__ __align__(16) ushort sB[3*ROWE];
    const int y = blockIdx.x, b = blockIdx.y;
    const int tid = threadIdx.x, lane = tid & 63, wv = tid >> 6;
    const int l16 = lane & 15, quad = lane >> 4;
    const int mh = wv >> 1, nh = wv & 1;

    // stage: one linear copy, 3168 uint4
    {
        const uint4* src = (const uint4*)(img + (size_t)(b*IMW + y)*ROWE);
        uint4* dst = (uint4*)sB;
        for (int i = tid; i < 3*ROWE/8; i += 256) dst[i] = src[i];
    }
    __syncthreads();

    // B column base per n-tile (clamped for waste lanes; slab xx = px + dx)
    int xBase[5];
    #pragma unroll
    for (int nt = 0; nt < 5; ++nt)
        xBase[nt] = min(nh*80 + nt*16 + l16, 129);

    const ushort* wA = wT + (size_t)(mh*64 + l16)*576 + quad*8;
    const int bQuad = quad*132;                    // cg offset inside (dy,h) group

    f32x4 acc[4][5];
    #pragma unroll
    for (int mt = 0; mt < 4; ++mt)
        #pragma unroll
        for (int nt = 0; nt < 5; ++nt)
            acc[mt][nt] = (f32x4){0.f, 0.f, 0.f, 0.f};

    short8 aCur[4];
    #pragma unroll
    for (int mt = 0; mt < 4; ++mt)
        aCur[mt] = *(const short8*)(wA + mt*16*576);

    #pragma unroll
    for (int s = 0; s < 18; ++s) {
        short8 aNxt[4];
        if (s < 17) {
            #pragma unroll
            for (int mt = 0; mt < 4; ++mt)
                aNxt[mt] = *(const short8*)(wA + mt*16*576 + (s+1)*32);
        }
        const int dydx = s >> 1, h = s & 1;
        const int dy = dydx / 3, dx = dydx - dy*3;
        const int gOff = ((dy*8 + h*4)*132 + dx)*8;
        short8 bf[5];
        #pragma unroll
        for (int nt = 0; nt < 5; ++nt)
            bf[nt] = *(const short8*)(sB + gOff + (bQuad + xBase[nt])*8);
        #pragma unroll
        for (int mt = 0; mt < 4; ++mt)
            #pragma unroll
            for (int nt = 0; nt < 5; ++nt)
                acc[mt][nt] = __builtin_amdgcn_mfma_f32_16x16x32_bf16(
                    aCur[mt], bf[nt], acc[mt][nt], 0, 0, 0);
        #pragma unroll
        for (int mt = 0; mt < 4; ++mt) aCur[mt] = aNxt[mt];
    }

    const size_t ob = (size_t)b*COUT*NPIX + (size_t)y*H_;
    #pragma unroll
    for (int mt = 0; mt < 4; ++mt) {
        #pragma unroll
        for (int r = 0; r < 4; ++r) {
            const int co = mh*64 + mt*16 + quad*4 + r;
            const float bv = bias[co];
            #pragma unroll
            for (int nt = 0; nt < 5; ++nt) {
                int p = nh*80 + nt*16 + l16;
                if (p < H_) {
                    float v = acc[mt][nt][r] + bv;
                    out[ob + (size_t)co*NPIX + p] = v > 0.f ? v : 0.f;
                }
            }
        }
    }
}

// ------------------------------------------------------------------------------
extern "C" void kernel_launch(void* const* d_in, const int* in_sizes, int n_in,
                              void* d_out, int out_size, void* d_ws, size_t ws_size,
                              hipStream_t stream)
{
    const float* x      = (const float*)d_in[0];
    const float* gamma  = (const float*)d_in[1];
    const float* beta   = (const float*)d_in[2];
    const float* conv_w = (const float*)d_in[3];
    const float* conv_b = (const float*)d_in[4];
    float* out = (float*)d_out;

    float*  part = (float*)d_ws;            // 1024 f32
    float*  abuf = part + 1024;             // 64
    float*  bbuf = abuf + 64;               // 64
    ushort* wT   = (ushort*)(bbuf + 64);    // 73728 bf16 (byte offset 4608)
    ushort* img  = wT + 73728;              // 8*132*8448 bf16 = 17,842,176 B

    bn_stage1<<<dim3(CIN, B_), 256, 0, stream>>>(x, part);
    wprep_bn<<<288, 256, 0, stream>>>(conv_w, part, gamma, beta, wT, abuf, bbuf);
    binfold<<<dim3(IMW, B_, 4), 256, 0, stream>>>(x, abuf, bbuf, img);
    conv_mfma<<<dim3(H_, B_), 256, 0, stream>>>(img, wT, conv_b, out);
}

// Round 6
// 185.574 us; speedup vs baseline: 1.0357x; 1.0357x over previous
//
#include <hip/hip_runtime.h>
#include <math.h>

#define B_    8
#define CIN   64
#define COUT  128
#define H_    130
#define NPIX  (H_*H_)            // 16900
#define NPX   (B_*NPIX)          // 135200 flat pixels
#define IMW   132                // padded img height (zero top/bottom rows)
#define SLABU 4608               // ushorts per (yy,xh) slab = 8 cg * 72 col * 8 ci

typedef __attribute__((ext_vector_type(8))) short short8;   // 8 bf16 (A/B frag)
typedef __attribute__((ext_vector_type(4))) float f32x4;    // MFMA acc

__device__ __forceinline__ ushort f2bf(float f) {
    uint u = __builtin_bit_cast(uint, f);
    uint r = (u + 0x7FFFu + ((u >> 16) & 1u)) >> 16;
    return (ushort)r;
}

// ---------------- BN stage 1: per-(c,b) plane partial sum/sumsq ---------------
__global__ __launch_bounds__(256) void bn_stage1(
    const float* __restrict__ x, float* __restrict__ part)
{
    const int c = blockIdx.x, b = blockIdx.y, tid = threadIdx.x;
    const float4* p = (const float4*)(x + ((size_t)b*CIN + c)*NPIX);
    float s = 0.f, q = 0.f;
    for (int i = tid; i < NPIX/4; i += 256) {   // 16900/4 = 4225 exactly
        float4 v = p[i];
        s += v.x + v.y + v.z + v.w;
        q += v.x*v.x + v.y*v.y + v.z*v.z + v.w*v.w;
    }
    #pragma unroll
    for (int off = 32; off; off >>= 1) { s += __shfl_down(s, off); q += __shfl_down(q, off); }
    __shared__ float ss[4], qq[4];
    if ((tid & 63) == 0) { ss[tid >> 6] = s; qq[tid >> 6] = q; }
    __syncthreads();
    if (tid == 0) {
        s = ss[0] + ss[1] + ss[2] + ss[3];
        q = qq[0] + qq[1] + qq[2] + qq[3];
        part[(c*B_ + b)*2]     = s;
        part[(c*B_ + b)*2 + 1] = q;
    }
}

// ------- fused: weight prep (f32 [co][ci][3][3] -> bf16 [co][dydx][ci]) -------
// ------- + BN stage 2 (combine partials -> affine a,b) on block 0 ------------
__global__ __launch_bounds__(256) void wprep_bn(
    const float* __restrict__ w, const float* __restrict__ part,
    const float* __restrict__ gamma, const float* __restrict__ beta,
    ushort* __restrict__ wT, float* __restrict__ abuf, float* __restrict__ bbuf)
{
    int i = blockIdx.x*256 + threadIdx.x;        // 288*256 = 73728 = 128*576
    int co = i / 576, k = i - co*576;
    int dydx = k >> 6, ci = k & 63;
    wT[i] = f2bf(w[co*576 + ci*9 + dydx]);
    if (blockIdx.x == 0 && threadIdx.x < 64) {
        int c = threadIdx.x;
        float s = 0.f, q = 0.f;
        for (int b = 0; b < B_; ++b) { s += part[(c*B_+b)*2]; q += part[(c*B_+b)*2+1]; }
        float mean = s * (1.0f/135200.f);
        float var  = q * (1.0f/135200.f) - mean*mean;
        float a = gamma[c] / sqrtf(var + 1e-4f);
        abuf[c] = a;
        bbuf[c] = beta[c] - mean * a;
    }
}

// -------- binfold v3: BN-apply + bin_active + col2im ---------------------------
// img layout: [b][yy(132)][xh(2)][cg(8)][col(72)][ci8] bf16.
//   col c of half xh <-> padded xx = 65*xh + c (c 0..67 written; 68..71 pad,
//   never read). xx=0/131 and rows yy=0/131 are the zero ring.
// grid z = 4 ci-groups of 16 (cg pair); each wave owns 4 ci, loads hoisted.
__global__ __launch_bounds__(256) void binfold(
    const float* __restrict__ x, const float* __restrict__ abuf,
    const float* __restrict__ bbuf, ushort* __restrict__ img)
{
    __shared__ __align__(16) ushort tile[H_*18];   // [xp][ci16 +2 pad]
    __shared__ float absrow[4][132];
    __shared__ float wsum[4][24];
    const int yy = blockIdx.x, b = blockIdx.y, zg = blockIdx.z;
    const int tid = threadIdx.x, wv = tid >> 6, lane = tid & 63;
    const int cgBase = zg*2;
    uint* u0 = (uint*)(img + ((size_t)(b*IMW + yy)*2)*SLABU);

    if (yy == 0 || yy == IMW-1) {                  // border row: zero our slice
        for (int i = tid; i < 1088; i += 256) {
            int xhh = i / 544, r = i - xhh*544, c = r >> 3, p = r & 7;
            u0[(size_t)xhh*(SLABU/2) + ((cgBase + (p>>2))*72 + c)*4 + (p&3)] = 0u;
        }
        return;
    }
    const int y = yy - 1;
    const float county = (float)min(min(y + 1, 3), H_ - y);

    // hoisted loads: 4 ci rows per wave, all issued up-front
    const int ci0 = zg*16 + wv*4;
    float v0[4], v1[4], v2[4];
    #pragma unroll
    for (int it = 0; it < 4; ++it) {
        const int ci = ci0 + it;
        const float* row = x + (((size_t)b*CIN + ci)*H_ + y)*H_;
        const float a = abuf[ci], bb = bbuf[ci];
        v0[it] = a*row[lane]      + bb;
        v1[it] = a*row[lane + 64] + bb;
        v2[it] = (lane < 2) ? (a*row[lane + 128] + bb) : 0.f;
    }

    #pragma unroll
    for (int it = 0; it < 4; ++it) {
        const int cl = wv*4 + it;                  // ci_l within block, 0..15
        absrow[wv][lane]      = fabsf(v0[it]);
        absrow[wv][lane + 64] = fabsf(v1[it]);
        if (lane < 2) absrow[wv][lane + 128] = fabsf(v2[it]);
        asm volatile("s_waitcnt lgkmcnt(0)" ::: "memory");
        if (lane < 24) {
            int j = lane >> 3, bx = lane & 7;
            int s = j + bx*16;
            float acc = 0.f;
            #pragma unroll
            for (int t = 0; t < 16; ++t) acc += absrow[wv][s + t];
            wsum[wv][j*8 + bx] = acc;
        }
        asm volatile("s_waitcnt lgkmcnt(0)" ::: "memory");
        #pragma unroll
        for (int rep = 0; rep < 3; ++rep) {
            int xp = lane + rep*64;
            if (xp < H_) {
                float v = (rep == 0) ? v0[it] : (rep == 1) ? v1[it] : v2[it];
                float sgn = (v > 0.f) ? 1.f : ((v < 0.f) ? -1.f : 0.f);
                float sum = 0.f;
                #pragma unroll
                for (int j = 0; j < 3; ++j) {
                    int ox = xp - j;
                    if ((unsigned)ox < 128u) sum += wsum[wv][j*8 + (ox >> 4)];
                }
                tile[xp*18 + cl] = f2bf(sgn * county * sum * 0.0625f);
            }
        }
        asm volatile("s_waitcnt lgkmcnt(0)" ::: "memory");   // absrow reuse guard
    }
    __syncthreads();
    // store our cg pair into both half-slabs (halo columns duplicated)
    const uint* tU = (const uint*)tile;
    for (int i = tid; i < 1088; i += 256) {
        int xhh = i / 544, r = i - xhh*544, c = r >> 3, p = r & 7;
        int xx = xhh*65 + c;
        if (xx > 131) continue;                    // xh=1, c=67 -> out of range
        uint v = 0u;
        if (xx != 0 && xx != 131) v = tU[(xx-1)*9 + p];
        u0[(size_t)xhh*(SLABU/2) + ((cgBase + (p>>2))*72 + c)*4 + (p&3)] = v;
    }
}

// ---------------- conv v4: half-row blocks, async DMA staging, A-prefetch -----
// Block = (xh, y, b). LDS = 3 dy-slabs of 9216 B, DMA'd as 27 x 1KB chunks via
// global_load_lds (width 16). 4 waves = co-quarters; wave = 32 co (2 mt) x
// 65 px (5 nt). K = 18 steps of 32 (dydx major, ci-half minor). A-prefetch
// ring depth 2 (~2 steps ~= 200 cyc >= L2 latency).
__global__ __launch_bounds__(256, 4) void conv_mfma(
    const ushort* __restrict__ img, const ushort* __restrict__ wT,
    const float* __restrict__ bias, float* __restrict__ out)
{
    __shared__ __align__(64) ushort sB[3*SLABU];   // 27648 B
    const int xh = blockIdx.x, y = blockIdx.y, b = blockIdx.z;
    const int tid = threadIdx.x, lane = tid & 63, q = tid >> 6;
    const int l16 = lane & 15, quad = lane >> 4;

    // ---- async DMA stage: 27 chunks of 1 KB, wave q takes chunks q, q+4, ...
    {
        const size_t rowBase = ((size_t)(b*IMW + y)*2 + xh);
        #pragma unroll
        for (int t = 0; t < 7; ++t) {
            int k = q + 4*t;
            if (k < 27) {
                int dy = (int)((unsigned)k / 9u), j = k - dy*9;
                const ushort* gs = img + (rowBase + (size_t)dy*2)*SLABU + j*512 + lane*8;
                ushort* ls = sB + k*512;
                __builtin_amdgcn_global_load_lds(
                    (const __attribute__((address_space(1))) uint*)gs,
                    (__attribute__((address_space(3))) uint*)ls, 16, 0, 0);
            }
        }
    }
    __syncthreads();

    const ushort* wA = wT + (size_t)(q*32 + l16)*576 + quad*8;
    short8 aP[3][2];
    #pragma unroll
    for (int mt = 0; mt < 2; ++mt) {
        aP[0][mt] = *(const short8*)(wA + mt*16*576);
        aP[1][mt] = *(const short8*)(wA + mt*16*576 + 32);
    }
    int colB[5];
    #pragma unroll
    for (int nt = 0; nt < 5; ++nt)
        colB[nt] = min(nt*16 + l16, 64);           // clamp: waste lanes of nt=4

    f32x4 acc[2][5];
    #pragma unroll
    for (int mt = 0; mt < 2; ++mt)
        #pragma unroll
        for (int nt = 0; nt < 5; ++nt)
            acc[mt][nt] = (f32x4){0.f, 0.f, 0.f, 0.f};

    #pragma unroll
    for (int s = 0; s < 18; ++s) {
        if (s < 16) {
            #pragma unroll
            for (int mt = 0; mt < 2; ++mt)
                aP[(s+2)%3][mt] = *(const short8*)(wA + mt*16*576 + (s+2)*32);
        }
        const int dydx = s >> 1, h = s & 1;
        const int dy = dydx / 3, dx = dydx - dy*3;
        const int base = dy*SLABU + ((h*4 + quad)*72 + dx)*8;
        short8 bf[5];
        #pragma unroll
        for (int nt = 0; nt < 5; ++nt)
            bf[nt] = *(const short8*)(sB + base + colB[nt]*8);
        #pragma unroll
        for (int mt = 0; mt < 2; ++mt)
            #pragma unroll
            for (int nt = 0; nt < 5; ++nt)
                acc[mt][nt] = __builtin_amdgcn_mfma_f32_16x16x32_bf16(
                    aP[s%3][mt], bf[nt], acc[mt][nt], 0, 0, 0);
    }

    const size_t ob = (size_t)b*COUT*NPIX + (size_t)y*H_ + xh*65;
    #pragma unroll
    for (int mt = 0; mt < 2; ++mt) {
        #pragma unroll
        for (int r = 0; r < 4; ++r) {
            const int co = q*32 + mt*16 + quad*4 + r;
            const float bv = bias[co];
            #pragma unroll
            for (int nt = 0; nt < 5; ++nt) {
                int p = nt*16 + l16;
                if (p < 65) {
                    float v = acc[mt][nt][r] + bv;
                    out[ob + (size_t)co*NPIX + p] = v > 0.f ? v : 0.f;
                }
            }
        }
    }
}

// ------------------------------------------------------------------------------
extern "C" void kernel_launch(void* const* d_in, const int* in_sizes, int n_in,
                              void* d_out, int out_size, void* d_ws, size_t ws_size,
                              hipStream_t stream)
{
    const float* x      = (const float*)d_in[0];
    const float* gamma  = (const float*)d_in[1];
    const float* beta   = (const float*)d_in[2];
    const float* conv_w = (const float*)d_in[3];
    const float* conv_b = (const float*)d_in[4];
    float* out = (float*)d_out;

    float*  part = (float*)d_ws;            // 1024 f32
    float*  abuf = part + 1024;             // 64
    float*  bbuf = abuf + 64;               // 64
    ushort* wT   = (ushort*)(bbuf + 64);    // 73728 bf16 (byte offset 4608)
    ushort* img  = wT + 73728;              // 8*132*2*4608 bf16 = 19,464,192 B

    bn_stage1<<<dim3(CIN, B_), 256, 0, stream>>>(x, part);
    wprep_bn<<<288, 256, 0, stream>>>(conv_w, part, gamma, beta, wT, abuf, bbuf);
    binfold<<<dim3(IMW, B_, 4), 256, 0, stream>>>(x, abuf, bbuf, img);
    conv_mfma<<<dim3(2, H_, B_), 256, 0, stream>>>(img, wT, conv_b, out);
}

// Round 7
// 167.285 us; speedup vs baseline: 1.1490x; 1.1093x over previous
//
#include <hip/hip_runtime.h>
#include <math.h>

#define B_    8
#define CIN   64
#define COUT  128
#define H_    130
#define NPIX  (H_*H_)            // 16900
#define NPX   (B_*NPIX)          // 135200 flat pixels
#define IMW   132                // padded img height (zero top/bottom rows)
#define SLABU 4608               // ushorts per (yy,xh) slab = 8 cg * 72 col * 8 ci
#define RSTRIP 4                 // output rows per conv block

typedef __attribute__((ext_vector_type(8))) short short8;   // 8 bf16 (A/B frag)
typedef __attribute__((ext_vector_type(4))) float f32x4;    // MFMA acc

__device__ __forceinline__ ushort f2bf(float f) {
    uint u = __builtin_bit_cast(uint, f);
    uint r = (u + 0x7FFFu + ((u >> 16) & 1u)) >> 16;
    return (ushort)r;
}

// ------ BN stage 1 (per-(c,b) plane sum/sumsq) + fused weight prep ------------
// grid (64,8) = 512 blocks; flat blocks 0..287 also convert one 256-elem chunk
// of conv_w into wT [co][dydx][ci] bf16 (independent work).
__global__ __launch_bounds__(256) void bnw_stage1(
    const float* __restrict__ x, const float* __restrict__ w,
    float* __restrict__ part, ushort* __restrict__ wT)
{
    const int c = blockIdx.x, b = blockIdx.y, tid = threadIdx.x;
    const int flat = b*64 + c;
    if (flat < 288) {                            // wprep: 288*256 = 73728
        int i = flat*256 + tid;
        int co = i / 576, k = i - co*576;
        int dydx = k >> 6, ci = k & 63;
        wT[i] = f2bf(w[co*576 + ci*9 + dydx]);
    }
    const float4* p = (const float4*)(x + ((size_t)b*CIN + c)*NPIX);
    float s = 0.f, q = 0.f;
    for (int i = tid; i < NPIX/4; i += 256) {    // 4225 exactly
        float4 v = p[i];
        s += v.x + v.y + v.z + v.w;
        q += v.x*v.x + v.y*v.y + v.z*v.z + v.w*v.w;
    }
    #pragma unroll
    for (int off = 32; off; off >>= 1) { s += __shfl_down(s, off); q += __shfl_down(q, off); }
    __shared__ float ss[4], qq[4];
    if ((tid & 63) == 0) { ss[tid >> 6] = s; qq[tid >> 6] = q; }
    __syncthreads();
    if (tid == 0) {
        s = ss[0] + ss[1] + ss[2] + ss[3];
        q = qq[0] + qq[1] + qq[2] + qq[3];
        part[(c*B_ + b)*2]     = s;
        part[(c*B_ + b)*2 + 1] = q;
    }
}

// -------- binfold v4: BN-apply + bin_active + col2im, stage2 fused ------------
// img layout: [b][yy(132)][xh(2)][cg(8)][col(72)][ci8] bf16.
//   col c of half xh <-> padded xx = 65*xh + c. Rows yy=0/131, cols xx=0/131
//   are the zero ring; cols 68..71 are pad (never read).
__global__ __launch_bounds__(256) void binfold(
    const float* __restrict__ x, const float* __restrict__ part,
    const float* __restrict__ gamma, const float* __restrict__ beta,
    ushort* __restrict__ img)
{
    __shared__ __align__(16) ushort tile[H_*18];   // [xp][ci16 +2 pad]
    __shared__ float absrow[4][132];
    __shared__ float wsum[4][24];
    __shared__ float sA[4][4], sBt[4][4];
    const int yy = blockIdx.x, b = blockIdx.y, zg = blockIdx.z;
    const int tid = threadIdx.x, wv = tid >> 6, lane = tid & 63;
    const int cgBase = zg*2;
    uint* u0 = (uint*)(img + ((size_t)(b*IMW + yy)*2)*SLABU);

    if (yy == 0 || yy == IMW-1) {                  // border row: zero our slice
        for (int i = tid; i < 1088; i += 256) {
            int xhh = i / 544, r = i - xhh*544, c = r >> 3, p = r & 7;
            u0[(size_t)xhh*(SLABU/2) + ((cgBase + (p>>2))*72 + c)*4 + (p&3)] = 0u;
        }
        return;
    }
    const int y = yy - 1;
    const float county = (float)min(min(y + 1, 3), H_ - y);

    // fused BN stage 2: lanes 0..3 derive affine a,b for this wave's 4 ci
    const int ci0 = zg*16 + wv*4;
    if (lane < 4) {
        int ci = ci0 + lane;
        float s = 0.f, q = 0.f;
        #pragma unroll
        for (int bb = 0; bb < B_; ++bb) {
            s += part[(ci*B_ + bb)*2];
            q += part[(ci*B_ + bb)*2 + 1];
        }
        float mean = s * (1.0f/135200.f);
        float var  = q * (1.0f/135200.f) - mean*mean;
        float a = gamma[ci] / sqrtf(var + 1e-4f);
        sA[wv][lane]  = a;
        sBt[wv][lane] = beta[ci] - mean * a;
    }
    asm volatile("s_waitcnt lgkmcnt(0)" ::: "memory");

    // hoisted loads: 4 ci rows per wave, all issued up-front
    float v0[4], v1[4], v2[4];
    #pragma unroll
    for (int it = 0; it < 4; ++it) {
        const int ci = ci0 + it;
        const float* row = x + (((size_t)b*CIN + ci)*H_ + y)*H_;
        const float a = sA[wv][it], bb = sBt[wv][it];
        v0[it] = a*row[lane]      + bb;
        v1[it] = a*row[lane + 64] + bb;
        v2[it] = (lane < 2) ? (a*row[lane + 128] + bb) : 0.f;
    }

    #pragma unroll
    for (int it = 0; it < 4; ++it) {
        const int cl = wv*4 + it;                  // ci_l within block, 0..15
        absrow[wv][lane]      = fabsf(v0[it]);
        absrow[wv][lane + 64] = fabsf(v1[it]);
        if (lane < 2) absrow[wv][lane + 128] = fabsf(v2[it]);
        asm volatile("s_waitcnt lgkmcnt(0)" ::: "memory");
        if (lane < 24) {
            int j = lane >> 3, bx = lane & 7;
            int s = j + bx*16;
            float acc = 0.f;
            #pragma unroll
            for (int t = 0; t < 16; ++t) acc += absrow[wv][s + t];
            wsum[wv][j*8 + bx] = acc;
        }
        asm volatile("s_waitcnt lgkmcnt(0)" ::: "memory");
        #pragma unroll
        for (int rep = 0; rep < 3; ++rep) {
            int xp = lane + rep*64;
            if (xp < H_) {
                float v = (rep == 0) ? v0[it] : (rep == 1) ? v1[it] : v2[it];
                float sgn = (v > 0.f) ? 1.f : ((v < 0.f) ? -1.f : 0.f);
                float sum = 0.f;
                #pragma unroll
                for (int j = 0; j < 3; ++j) {
                    int ox = xp - j;
                    if ((unsigned)ox < 128u) sum += wsum[wv][j*8 + (ox >> 4)];
                }
                tile[xp*18 + cl] = f2bf(sgn * county * sum * 0.0625f);
            }
        }
        asm volatile("s_waitcnt lgkmcnt(0)" ::: "memory");   // absrow reuse guard
    }
    __syncthreads();
    // store our cg pair into both half-slabs (halo columns duplicated)
    const uint* tU = (const uint*)tile;
    for (int i = tid; i < 1088; i += 256) {
        int xhh = i / 544, r = i - xhh*544, c = r >> 3, p = r & 7;
        int xx = xhh*65 + c;
        if (xx > 131) continue;                    // xh=1, c=67 -> out of range
        uint v = 0u;
        if (xx != 0 && xx != 131) v = tU[(xx-1)*9 + p];
        u0[(size_t)xhh*(SLABU/2) + ((cgBase + (p>>2))*72 + c)*4 + (p&3)] = v;
    }
}

// ---------------- conv v5: A-in-registers, 4-row strips, one-shot DMA ---------
// Block = (xh, ystrip, b). LDS ring: 6 slabs (padded rows y0..y0+5, 55.3 KB)
// staged once via 54 x 1KB global_load_lds chunks. Each wave holds all 36 A
// fragments (2 mt x 18 k-steps, 144 VGPRs) for its 32 co; zero global loads
// in the k-loop. 4 waves = co-quarters; wave tile = 32 co x 65 px per row.
__global__ __launch_bounds__(256, 2) void conv_mfma(
    const ushort* __restrict__ img, const ushort* __restrict__ wT,
    const float* __restrict__ bias, float* __restrict__ out)
{
    __shared__ __align__(64) ushort sB[6*SLABU];   // 55296 B
    const int xh = blockIdx.x, ys = blockIdx.y, b = blockIdx.z;
    const int y0 = ys*RSTRIP;
    const int tid = threadIdx.x, lane = tid & 63, q = tid >> 6;
    const int l16 = lane & 15, quad = lane >> 4;

    // ---- one-shot async DMA: 54 chunks of 1 KB (SLABU = 9*512)
    #pragma unroll
    for (int t = 0; t < 14; ++t) {
        int k = q + 4*t;
        if (k < 54) {
            int sl = (int)((unsigned)k / 9u), j = k - sl*9;
            int yy = min(y0 + sl, IMW-1);          // clamp: last strip tail
            const ushort* gs = img + ((size_t)(b*IMW + yy)*2 + xh)*SLABU
                               + j*512 + lane*8;
            __builtin_amdgcn_global_load_lds(
                (const __attribute__((address_space(1))) uint*)gs,
                (__attribute__((address_space(3))) uint*)(sB + k*512), 16, 0, 0);
        }
    }

    // ---- A fragments: load all 36 once (completes at the barrier's vmcnt(0))
    const ushort* wA = wT + (size_t)(q*32 + l16)*576 + quad*8;
    short8 aReg[36];
    #pragma unroll
    for (int mt = 0; mt < 2; ++mt)
        #pragma unroll
        for (int s = 0; s < 18; ++s)
            aReg[mt*18 + s] = *(const short8*)(wA + mt*16*576 + s*32);

    float bv[8];
    #pragma unroll
    for (int mt = 0; mt < 2; ++mt)
        #pragma unroll
        for (int rr = 0; rr < 4; ++rr)
            bv[mt*4 + rr] = bias[q*32 + mt*16 + quad*4 + rr];

    int colB[5];
    #pragma unroll
    for (int nt = 0; nt < 5; ++nt)
        colB[nt] = min(nt*16 + l16, 64);           // clamp waste lanes of nt=4

    __syncthreads();

    #pragma unroll
    for (int r = 0; r < RSTRIP; ++r) {
        const int y = y0 + r;
        if (y < H_) {
            f32x4 acc[2][5];
            #pragma unroll
            for (int mt = 0; mt < 2; ++mt)
                #pragma unroll
                for (int nt = 0; nt < 5; ++nt)
                    acc[mt][nt] = (f32x4){0.f, 0.f, 0.f, 0.f};

            #pragma unroll
            for (int s = 0; s < 18; ++s) {
                const int dydx = s >> 1, h = s & 1;
                const int dy = dydx / 3, dx = dydx - dy*3;
                const int base = (r + dy)*SLABU + ((h*4 + quad)*72 + dx)*8;
                short8 bf[5];
                #pragma unroll
                for (int nt = 0; nt < 5; ++nt)
                    bf[nt] = *(const short8*)(sB + base + colB[nt]*8);
                #pragma unroll
                for (int mt = 0; mt < 2; ++mt)
                    #pragma unroll
                    for (int nt = 0; nt < 5; ++nt)
                        acc[mt][nt] = __builtin_amdgcn_mfma_f32_16x16x32_bf16(
                            aReg[mt*18 + s], bf[nt], acc[mt][nt], 0, 0, 0);
            }

            const size_t ob = (size_t)b*COUT*NPIX + (size_t)y*H_ + xh*65;
            #pragma unroll
            for (int mt = 0; mt < 2; ++mt) {
                #pragma unroll
                for (int rr = 0; rr < 4; ++rr) {
                    const int co = q*32 + mt*16 + quad*4 + rr;
                    #pragma unroll
                    for (int nt = 0; nt < 5; ++nt) {
                        int p = nt*16 + l16;
                        if (p < 65) {
                            float v = acc[mt][nt][rr] + bv[mt*4 + rr];
                            out[ob + (size_t)co*NPIX + p] = v > 0.f ? v : 0.f;
                        }
                    }
                }
            }
        }
    }
}

// ------------------------------------------------------------------------------
extern "C" void kernel_launch(void* const* d_in, const int* in_sizes, int n_in,
                              void* d_out, int out_size, void* d_ws, size_t ws_size,
                              hipStream_t stream)
{
    const float* x      = (const float*)d_in[0];
    const float* gamma  = (const float*)d_in[1];
    const float* beta   = (const float*)d_in[2];
    const float* conv_w = (const float*)d_in[3];
    const float* conv_b = (const float*)d_in[4];
    float* out = (float*)d_out;

    float*  part = (float*)d_ws;            // 1024 f32
    ushort* wT   = (ushort*)(part + 1024);  // 73728 bf16 (byte offset 4096)
    ushort* img  = wT + 73728;              // 8*132*2*4608 bf16 = 19,464,192 B

    bnw_stage1<<<dim3(CIN, B_), 256, 0, stream>>>(x, conv_w, part, wT);
    binfold<<<dim3(IMW, B_, 4), 256, 0, stream>>>(x, part, gamma, beta, img);
    conv_mfma<<<dim3(2, (H_ + RSTRIP - 1)/RSTRIP, B_), 256, 0, stream>>>(img, wT, conv_b, out);
}